// Round 8
// baseline (369.996 us; speedup 1.0000x reference)
//
#include <hip/hip_runtime.h>

// Problem constants (fixed instance):
//   B=128 graphs, N=1024 nodes/graph, F=128 in-feats, D=256 hidden, E=8192 edges/graph
#define NNODES   1024
#define NGRAPH   128
#define NTOTAL   (NNODES * NGRAPH)   // 131072
#define FEAT_IN  128
#define DHID     256
#define ECAP     (16384 + NNODES)    // CSR capacity

typedef __attribute__((ext_vector_type(8))) short bf16x8;
typedef __attribute__((ext_vector_type(4))) float f32x4;
typedef __attribute__((ext_vector_type(4))) unsigned short us4;
typedef __attribute__((ext_vector_type(8))) unsigned short us8;

__device__ __forceinline__ unsigned short f2bf(float f) {
    unsigned int u = __float_as_uint(f);
    u += 0x7fffu + ((u >> 16) & 1u);           // RNE
    return (unsigned short)(u >> 16);
}
__device__ __forceinline__ float bf2f(unsigned short s) {
    return __uint_as_float(((unsigned int)s) << 16);
}
__device__ __forceinline__ float blo(unsigned int u) { return __uint_as_float(u << 16); }
__device__ __forceinline__ float bhi(unsigned int u) { return __uint_as_float(u & 0xffff0000u); }

// ---------------- build: degree, dinv, CSR (by dst, incl self-loops), rowsum, zero stats --------
__global__ __launch_bounds__(1024) void build_kernel(
    const int* __restrict__ ei, int E,
    int* __restrict__ offs, int* __restrict__ ecol, float* __restrict__ ew,
    float* __restrict__ rowsum,
    float* __restrict__ stats /* 1024 floats zeroed */)
{
    __shared__ int scnt[NNODES];
    __shared__ int bufA[NNODES];
    __shared__ int bufB[NNODES];
    __shared__ float sdinv[NNODES];
    const int t = threadIdx.x;

    scnt[t] = 1;              // self-loop
    stats[t] = 0.0f;
    __syncthreads();

    for (int e = t; e < E; e += 1024)
        atomicAdd(&scnt[ei[E + e]], 1);   // dst = ei[1][e]
    __syncthreads();

    const int deg = scnt[t];
    const float di = rsqrtf((float)deg);
    sdinv[t] = di;
    bufA[t] = deg;
    __syncthreads();

    int* src = bufA; int* dst = bufB;
    for (int d = 1; d < NNODES; d <<= 1) {
        dst[t] = src[t] + (t >= d ? src[t - d] : 0);
        __syncthreads();
        int* tmp = src; src = dst; dst = tmp;
    }
    const int excl = src[t] - deg;
    offs[t] = excl;
    if (t == NNODES - 1) offs[NNODES] = src[t];

    ecol[excl] = t;
    ew[excl] = di * di;
    scnt[t] = excl + 1;

    float* fb = (float*)bufB;            // rowsum accumulator (bufB free post-scan, 10 iters even)
    fb[t] = di * di;                     // self-loop weight
    __syncthreads();

    for (int e = t; e < E; e += 1024) {
        const int s = ei[e];
        const int d = ei[E + e];
        const int pos = atomicAdd(&scnt[d], 1);
        const float wv = sdinv[s] * sdinv[d];
        ecol[pos] = s;
        ew[pos] = wv;
        atomicAdd(&fb[d], wv);
    }
    __syncthreads();
    rowsum[t] = fb[t];
}

// ---------------- W1 prep (no BN): Wt[n][k] = bf16(W[k][n]) ; cvec[n] = 0 ------------------------
__global__ __launch_bounds__(256) void wprep_kernel(
    const float* __restrict__ W, unsigned short* __restrict__ Wt,
    float* __restrict__ cvec, int K)
{
    const int n = blockIdx.x, k = threadIdx.x;
    if (k < K) Wt[(size_t)n * K + k] = f2bf(W[(size_t)k * DHID + n]);
    if (k == 0) cvec[n] = 0.0f;
}

// ---------------- fused BN-finalize + W prep -----------------------------------------------------
__global__ __launch_bounds__(256) void bnwprep_kernel(
    const float* __restrict__ stats, const float* __restrict__ gamma,
    const float* __restrict__ beta, const float* __restrict__ W,
    unsigned short* __restrict__ Wt, float* __restrict__ cvec)
{
    __shared__ float red[256];
    const int n = blockIdx.x, k = threadIdx.x;
    const float nn = (float)NTOTAL;
    const float mean = stats[k] / nn;
    const float var = stats[256 + k] / nn - mean * mean;
    const float sc = gamma[k] * rsqrtf(var + 1e-5f);
    const float sh = beta[k] - mean * sc;
    const float wv = W[(size_t)k * DHID + n];
    Wt[(size_t)n * DHID + k] = f2bf(sc * wv);
    red[k] = sh * wv;
    __syncthreads();
    for (int s = 128; s > 0; s >>= 1) {
        if (k < s) red[k] += red[k + s];
        __syncthreads();
    }
    if (k == 0) cvec[n] = red[0];
}

// ---------------- MFMA GEMM: C[M][256] = bf16(A @ Wt^T) ------------------------------------------
// 128x128 tile, BK=64, 4 waves (2x2), 4x4 frags of 16x16x32.
// CVT=0: A bf16 via global_load_lds w16, double-buffered. CVT=1: A fp32 reg-staged+cvt.
// Block decode (1D grid 2048): n-tile pair of an m-panel on the same XCD (A L2 reuse).
#define GBK 64

template<bool CVT>
__global__ __launch_bounds__(256) void mgemm_kernel(
    const void* __restrict__ Ain,
    const unsigned short* __restrict__ Wt,
    unsigned short* __restrict__ C, int K)
{
    constexpr int NBUF = CVT ? 1 : 2;
    __shared__ unsigned short sA[NBUF][128 * GBK];
    __shared__ unsigned short sB[NBUF][128 * GBK];

    const int t = threadIdx.x;
    const int bid = blockIdx.x;
    const int xcd = bid & 7, kk_ = bid >> 3;
    const int m0 = ((kk_ >> 1) * 8 + xcd) * 128;
    const int n0 = (kk_ & 1) * 128;

    const int w = t >> 6, lane = t & 63;
    const int wr = w >> 1, wc = w & 1;
    const int lr = lane & 15, lk = lane >> 4;

    const int srow = lane >> 3;               // 0..7 within the 8-row group
    const int seg_src = (lane & 7) ^ srow;    // inverse-swizzled source segment

    f32x4 acc[4][4];
    #pragma unroll
    for (int i = 0; i < 4; ++i)
        #pragma unroll
        for (int j = 0; j < 4; ++j)
            acc[i][j] = (f32x4){0.f, 0.f, 0.f, 0.f};

    const int nsteps = K >> 6;

    auto stageB = [&](int buf, int k0) {
        #pragma unroll
        for (int i = 0; i < 4; ++i) {
            const int row = (w * 4 + i) * 8 + srow;
            const unsigned short* gb = Wt + (size_t)(n0 + row) * K + k0 + seg_src * 8;
            __builtin_amdgcn_global_load_lds(
                (const __attribute__((address_space(1))) unsigned int*)gb,
                (__attribute__((address_space(3))) unsigned int*)&sB[buf][(w * 4 + i) * 512],
                16, 0, 0);
        }
    };
    auto stageA_lds = [&](int buf, int k0) {
        #pragma unroll
        for (int i = 0; i < 4; ++i) {
            const int row = (w * 4 + i) * 8 + srow;
            const unsigned short* ga = (const unsigned short*)Ain + (size_t)(m0 + row) * K + k0 + seg_src * 8;
            __builtin_amdgcn_global_load_lds(
                (const __attribute__((address_space(1))) unsigned int*)ga,
                (__attribute__((address_space(3))) unsigned int*)&sA[buf][(w * 4 + i) * 512],
                16, 0, 0);
        }
    };

    auto compute = [&](int buf) {
        const char* pa = (const char*)sA[buf];
        const char* pb = (const char*)sB[buf];
        #pragma unroll
        for (int ks = 0; ks < 2; ++ks) {
            bf16x8 af[4], bfv[4];
            #pragma unroll
            for (int f = 0; f < 4; ++f) {
                const int ra = wr * 64 + f * 16 + lr;
                af[f] = *(const bf16x8*)(pa + ra * 128 + ((ks * 64 + lk * 16) ^ ((ra & 7) << 4)));
                const int rb = wc * 64 + f * 16 + lr;
                bfv[f] = *(const bf16x8*)(pb + rb * 128 + ((ks * 64 + lk * 16) ^ ((rb & 7) << 4)));
            }
            #pragma unroll
            for (int mf = 0; mf < 4; ++mf)
                #pragma unroll
                for (int nf = 0; nf < 4; ++nf)
                    acc[mf][nf] = __builtin_amdgcn_mfma_f32_16x16x32_bf16(
                        af[mf], bfv[nf], acc[mf][nf], 0, 0, 0);
        }
    };

    if constexpr (CVT) {
        const float* Af = (const float*)Ain;
        const int r = t >> 1, kh = (t & 1) * 32;   // this thread: row r, k-range [kh, kh+32)
        for (int s = 0; s < nsteps; ++s) {
            if (s > 0) __syncthreads();            // protect buffers from previous compute
            stageB(0, s * GBK);
            const float* ga = Af + (size_t)(m0 + r) * K + s * GBK + kh;
            #pragma unroll
            for (int j = 0; j < 4; ++j) {
                const float4 v0 = *(const float4*)(ga + j * 8);
                const float4 v1 = *(const float4*)(ga + j * 8 + 4);
                us8 o;
                o[0] = f2bf(v0.x); o[1] = f2bf(v0.y); o[2] = f2bf(v0.z); o[3] = f2bf(v0.w);
                o[4] = f2bf(v1.x); o[5] = f2bf(v1.y); o[6] = f2bf(v1.z); o[7] = f2bf(v1.w);
                const int slot = ((kh >> 3) + j) ^ (r & 7);
                *(us8*)&sA[0][r * 64 + slot * 8] = o;
            }
            __syncthreads();                       // drains B vmcnt + A lds writes
            compute(0);
        }
    } else {
        stageA_lds(0, 0);
        stageB(0, 0);
        __syncthreads();
        for (int s = 0; s < nsteps; ++s) {
            if (s + 1 < nsteps) { stageA_lds((s + 1) & 1, (s + 1) * GBK); stageB((s + 1) & 1, (s + 1) * GBK); }
            compute(s & 1);
            __syncthreads();
        }
    }

    // C/D layout: col = lane&15, row = (lane>>4)*4 + reg
    #pragma unroll
    for (int mf = 0; mf < 4; ++mf) {
        const int rbase = m0 + wr * 64 + mf * 16 + lk * 4;
        #pragma unroll
        for (int nf = 0; nf < 4; ++nf) {
            const int c = n0 + wc * 64 + nf * 16 + lr;
            #pragma unroll
            for (int r = 0; r < 4; ++r)
                C[(size_t)(rbase + r) * DHID + c] = f2bf(acc[mf][nf][r]);
        }
    }
}

// ---------------- SpMM: h = relu(Anorm @ hw + rowsum*c + b) --------------------------------------
// 8 feats/lane (16B uint4 gathers); a 256-feat row spans 32 lanes, so each wave
// processes a NODE PAIR (lanes 0-31 even node, 32-63 odd node): half the load
// instructions, 2 gather rows in flight per wave. Loop bound = max of the pair's
// edge counts (wave-uniform), predicated per half. Even/odd edge 2-deep unroll.
#define NB 16
#define ECAPB 512

template<bool STATS, bool OUTF32>
__global__ __launch_bounds__(256) void spmm_kernel(
    const unsigned short* __restrict__ hw, const float* __restrict__ bias,
    const float* __restrict__ rowsum, const float* __restrict__ cvec,
    void* __restrict__ hout, float* __restrict__ partials,
    const int* __restrict__ offs, const int* __restrict__ ecol,
    const float* __restrict__ ew)
{
    __shared__ int se[ECAPB];
    __shared__ float swt[ECAPB];
    __shared__ int soff[NB + 1];
    __shared__ float spartS[4][256];
    __shared__ float spartQ[4][256];

    const int b = blockIdx.x;                 // 8192 blocks
    const int xcd = b & 7;
    const int idx = b >> 3;
    const int g  = (idx >> 6) * 8 + xcd;      // all 64 blocks of graph g on one XCD
    const int nb = (idx & 63) * NB;
    const int t = threadIdx.x;
    const int w = t >> 6, lane = t & 63;
    const int h = lane >> 5;                  // half-wave: node parity
    const int f0 = (lane & 31) * 8;           // this lane's 8 features
    const unsigned short* __restrict__ hwg = hw + (size_t)g * NNODES * DHID;

    if (t <= NB) soff[t] = offs[nb + t];
    __syncthreads();
    const int base = soff[0];
    const int tot = soff[NB] - base;          // ~150, cap 512
    for (int e = t; e < tot; e += 256) { se[e] = ecol[base + e]; swt[e] = ew[base + e]; }
    __syncthreads();

    float bv[8], cv[8];
    *(float4*)&bv[0] = *(const float4*)(bias + f0);
    *(float4*)&bv[4] = *(const float4*)(bias + f0 + 4);
    *(float4*)&cv[0] = *(const float4*)(cvec + f0);
    *(float4*)&cv[4] = *(const float4*)(cvec + f0 + 4);
    float ps[8] = {0,0,0,0,0,0,0,0}, pq[8] = {0,0,0,0,0,0,0,0};

    #pragma unroll
    for (int j = 0; j < 2; ++j) {
        const int ia = w * 4 + j * 2;         // even node of this wave's pair
        const int i  = ia + h;                // this half's node
        const int s  = soff[i] - base;
        const int cnt = soff[i + 1] - soff[i];
        const int cmax = max(soff[ia + 1] - soff[ia], soff[ia + 2] - soff[ia + 1]);
        const float rs = rowsum[nb + i];
        float a[8] = {0,0,0,0,0,0,0,0}, a2[8] = {0,0,0,0,0,0,0,0};
        #pragma unroll 1
        for (int k = 0; k < cmax; k += 2) {
            if (k < cnt) {
                const int e = s + k;
                const uint4 u = *(const uint4*)(hwg + (size_t)se[e] * DHID + f0);
                const float wv = swt[e];
                a[0] = fmaf(wv, blo(u.x), a[0]); a[1] = fmaf(wv, bhi(u.x), a[1]);
                a[2] = fmaf(wv, blo(u.y), a[2]); a[3] = fmaf(wv, bhi(u.y), a[3]);
                a[4] = fmaf(wv, blo(u.z), a[4]); a[5] = fmaf(wv, bhi(u.z), a[5]);
                a[6] = fmaf(wv, blo(u.w), a[6]); a[7] = fmaf(wv, bhi(u.w), a[7]);
            }
            if (k + 1 < cnt) {
                const int e = s + k + 1;
                const uint4 u = *(const uint4*)(hwg + (size_t)se[e] * DHID + f0);
                const float wv = swt[e];
                a2[0] = fmaf(wv, blo(u.x), a2[0]); a2[1] = fmaf(wv, bhi(u.x), a2[1]);
                a2[2] = fmaf(wv, blo(u.y), a2[2]); a2[3] = fmaf(wv, bhi(u.y), a2[3]);
                a2[4] = fmaf(wv, blo(u.z), a2[4]); a2[5] = fmaf(wv, bhi(u.z), a2[5]);
                a2[6] = fmaf(wv, blo(u.w), a2[6]); a2[7] = fmaf(wv, bhi(u.w), a2[7]);
            }
        }
        float v[8];
        #pragma unroll
        for (int q = 0; q < 8; ++q)
            v[q] = fmaxf(fmaf(rs, cv[q], a[q] + a2[q]) + bv[q], 0.0f);

        const size_t orow = (size_t)g * NNODES + nb + i;
        if (OUTF32) {
            float* op = (float*)hout + orow * DHID + f0;
            *(float4*)op       = make_float4(v[0], v[1], v[2], v[3]);
            *(float4*)(op + 4) = make_float4(v[4], v[5], v[6], v[7]);
        } else {
            us8 o;
            #pragma unroll
            for (int q = 0; q < 8; ++q) o[q] = f2bf(v[q]);
            *(us8*)((unsigned short*)hout + orow * DHID + f0) = o;
        }
        if (STATS) {
            #pragma unroll
            for (int q = 0; q < 8; ++q) { ps[q] += v[q]; pq[q] += v[q] * v[q]; }
        }
    }

    if (STATS) {
        // combine the two halves (same features, different nodes), then per-wave slab
        #pragma unroll
        for (int q = 0; q < 8; ++q) {
            ps[q] += __shfl_xor(ps[q], 32);
            pq[q] += __shfl_xor(pq[q], 32);
        }
        if (h == 0) {
            #pragma unroll
            for (int q = 0; q < 8; ++q) { spartS[w][f0 + q] = ps[q]; spartQ[w][f0 + q] = pq[q]; }
        }
        __syncthreads();
        const float ss = spartS[0][t] + spartS[1][t] + spartS[2][t] + spartS[3][t];
        const float sq = spartQ[0][t] + spartQ[1][t] + spartQ[2][t] + spartQ[3][t];
        partials[(size_t)b * 512 + t] = ss;
        partials[(size_t)b * 512 + 256 + t] = sq;
    }
}

// ---------------- stats reduce ------------------------------------------------------------------
__global__ __launch_bounds__(256) void reduce_kernel(
    const float* __restrict__ partials, float* __restrict__ stats, int P)
{
    const int t = threadIdx.x;
    const int per = P / gridDim.x;
    const int p0 = blockIdx.x * per;
    float s = 0.0f, q = 0.0f;
    for (int p = p0; p < p0 + per; ++p) {
        s += partials[(size_t)p * 512 + t];
        q += partials[(size_t)p * 512 + 256 + t];
    }
    atomicAdd(&stats[t], s);
    atomicAdd(&stats[256 + t], q);
}

// ---------------- launch -------------------------------------------------------------------------
extern "C" void kernel_launch(void* const* d_in, const int* in_sizes, int n_in,
                              void* d_out, int out_size, void* d_ws, size_t ws_size,
                              hipStream_t stream)
{
    const float* x      = (const float*)d_in[0];
    const int*   ei     = (const int*)d_in[1];
    const float* W1     = (const float*)d_in[3];
    const float* b1     = (const float*)d_in[4];
    const float* W2     = (const float*)d_in[5];
    const float* b2     = (const float*)d_in[6];
    const float* W3     = (const float*)d_in[7];
    const float* b3     = (const float*)d_in[8];
    const float* gamma1 = (const float*)d_in[9];
    const float* beta1  = (const float*)d_in[10];
    const float* gamma2 = (const float*)d_in[11];
    const float* beta2  = (const float*)d_in[12];
    float* out = (float*)d_out;

    const int E = in_sizes[1] / 2;   // 8192

    // workspace layout (total ~152 MB)
    char* w = (char*)d_ws;
    unsigned short* hA = (unsigned short*)w;                 // h bf16 (67 MB)
    unsigned short* hw = (unsigned short*)(w + 67108864);    // 67 MB
    float* partials    = (float*)(w + 134217728);            // 16.8 MB
    char* meta = w + 150994944;
    int*   offs   = (int*)meta;            meta += 4352;
    int*   ecol   = (int*)meta;            meta += ECAP * 4;
    float* ewt    = (float*)meta;          meta += ECAP * 4;
    float* stats1 = (float*)meta;          meta += 512 * 4;   // stats1+stats2 contiguous (zeroed by build)
    float* stats2 = (float*)meta;          meta += 512 * 4;
    float* rowsum = (float*)meta;          meta += NNODES * 4;
    float* cvec1  = (float*)meta;          meta += 256 * 4;
    float* cvec2  = (float*)meta;          meta += 256 * 4;
    float* cvec3  = (float*)meta;          meta += 256 * 4;
    unsigned short* wt1 = (unsigned short*)meta;  meta += 256 * 128 * 2;
    unsigned short* wt2 = (unsigned short*)meta;  meta += 256 * 256 * 2;
    unsigned short* wt3 = (unsigned short*)meta;  meta += 256 * 256 * 2;

    const int GG = 2048;                 // 1D GEMM grid (pairing swizzle decoded in-kernel)
    const int P  = NTOTAL / NB;          // 8192

    build_kernel<<<1, 1024, 0, stream>>>(ei, E, offs, ecol, ewt, rowsum, stats1);
    wprep_kernel<<<DHID, 256, 0, stream>>>(W1, wt1, cvec1, FEAT_IN);

    // Layer 1 (x fp32 converted in-GEMM)
    mgemm_kernel<true><<<GG, 256, 0, stream>>>(x, wt1, hw, FEAT_IN);
    spmm_kernel<true, false><<<P, 256, 0, stream>>>(hw, b1, rowsum, cvec1, hA, partials, offs, ecol, ewt);
    reduce_kernel<<<64, 256, 0, stream>>>(partials, stats1, P);
    bnwprep_kernel<<<DHID, 256, 0, stream>>>(stats1, gamma1, beta1, W2, wt2, cvec2);

    // Layer 2
    mgemm_kernel<false><<<GG, 256, 0, stream>>>(hA, wt2, hw, DHID);
    spmm_kernel<true, false><<<P, 256, 0, stream>>>(hw, b2, rowsum, cvec2, hA, partials, offs, ecol, ewt);
    reduce_kernel<<<64, 256, 0, stream>>>(partials, stats2, P);
    bnwprep_kernel<<<DHID, 256, 0, stream>>>(stats2, gamma2, beta2, W3, wt3, cvec3);

    // Layer 3 (fp32 output, no stats)
    mgemm_kernel<false><<<GG, 256, 0, stream>>>(hA, wt3, hw, DHID);
    spmm_kernel<false, true><<<P, 256, 0, stream>>>(hw, b3, rowsum, cvec3, out, nullptr, offs, ecol, ewt);
}

// Round 10
// 349.106 us; speedup vs baseline: 1.0598x; 1.0598x over previous
//
#include <hip/hip_runtime.h>

// Problem constants (fixed instance):
//   B=128 graphs, N=1024 nodes/graph, F=128 in-feats, D=256 hidden, E=8192 edges/graph
#define NNODES   1024
#define NGRAPH   128
#define NTOTAL   (NNODES * NGRAPH)   // 131072
#define FEAT_IN  128
#define DHID     256
#define ECAP     (16384 + NNODES)    // CSR capacity

typedef __attribute__((ext_vector_type(8))) short bf16x8;
typedef __attribute__((ext_vector_type(4))) float f32x4;
typedef __attribute__((ext_vector_type(4))) unsigned short us4;
typedef __attribute__((ext_vector_type(8))) unsigned short us8;

__device__ __forceinline__ unsigned short f2bf(float f) {
    unsigned int u = __float_as_uint(f);
    u += 0x7fffu + ((u >> 16) & 1u);           // RNE
    return (unsigned short)(u >> 16);
}
__device__ __forceinline__ float blo(unsigned int u) { return __uint_as_float(u << 16); }
__device__ __forceinline__ float bhi(unsigned int u) { return __uint_as_float(u & 0xffff0000u); }

// ---------------- build: degree, CSR by dst (incl self-loops), packed (col,weight), rowsum ------
__global__ __launch_bounds__(1024) void build_kernel(
    const int* __restrict__ ei, int E,
    int* __restrict__ offs, uint2* __restrict__ ecw,
    float* __restrict__ rowsum,
    float* __restrict__ stats /* 1024 floats zeroed */)
{
    __shared__ int scnt[NNODES];
    __shared__ int bufA[NNODES];
    __shared__ int bufB[NNODES];
    __shared__ float sdinv[NNODES];
    const int t = threadIdx.x;

    scnt[t] = 1;              // self-loop
    stats[t] = 0.0f;
    __syncthreads();

    for (int e = t; e < E; e += 1024)
        atomicAdd(&scnt[ei[E + e]], 1);   // dst = ei[1][e]
    __syncthreads();

    const int deg = scnt[t];
    const float di = rsqrtf((float)deg);
    sdinv[t] = di;
    bufA[t] = deg;
    __syncthreads();

    int* src = bufA; int* dst = bufB;
    for (int d = 1; d < NNODES; d <<= 1) {
        dst[t] = src[t] + (t >= d ? src[t - d] : 0);
        __syncthreads();
        int* tmp = src; src = dst; dst = tmp;
    }
    const int excl = src[t] - deg;
    offs[t] = excl;
    if (t == NNODES - 1) offs[NNODES] = src[t];

    ecw[excl] = make_uint2((unsigned)t, __float_as_uint(di * di));   // self loop first
    scnt[t] = excl + 1;

    float* fb = (float*)bufB;            // rowsum accumulator (bufB free post-scan, 10 iters even)
    fb[t] = di * di;                     // self-loop weight
    __syncthreads();

    for (int e = t; e < E; e += 1024) {
        const int s = ei[e];
        const int d = ei[E + e];
        const int pos = atomicAdd(&scnt[d], 1);
        const float wv = sdinv[s] * sdinv[d];
        ecw[pos] = make_uint2((unsigned)s, __float_as_uint(wv));
        atomicAdd(&fb[d], wv);
    }
    __syncthreads();
    rowsum[t] = fb[t];
}

// ---------------- W1 prep (no BN): Wt[n][k] = bf16(W[k][n]) ; cvec[n] = 0 ------------------------
__global__ __launch_bounds__(256) void wprep_kernel(
    const float* __restrict__ W, unsigned short* __restrict__ Wt,
    float* __restrict__ cvec, int K)
{
    const int n = blockIdx.x, k = threadIdx.x;
    if (k < K) Wt[(size_t)n * K + k] = f2bf(W[(size_t)k * DHID + n]);
    if (k == 0) cvec[n] = 0.0f;
}

// ---------------- fused BN-finalize + W prep -----------------------------------------------------
__global__ __launch_bounds__(256) void bnwprep_kernel(
    const float* __restrict__ stats, const float* __restrict__ gamma,
    const float* __restrict__ beta, const float* __restrict__ W,
    unsigned short* __restrict__ Wt, float* __restrict__ cvec)
{
    __shared__ float red[256];
    const int n = blockIdx.x, k = threadIdx.x;
    const float nn = (float)NTOTAL;
    const float mean = stats[k] / nn;
    const float var = stats[256 + k] / nn - mean * mean;
    const float sc = gamma[k] * rsqrtf(var + 1e-5f);
    const float sh = beta[k] - mean * sc;
    const float wv = W[(size_t)k * DHID + n];
    Wt[(size_t)n * DHID + k] = f2bf(sc * wv);
    red[k] = sh * wv;
    __syncthreads();
    for (int s = 128; s > 0; s >>= 1) {
        if (k < s) red[k] += red[k + s];
        __syncthreads();
    }
    if (k == 0) cvec[n] = red[0];
}

// ---------------- MFMA GEMM: C[M][256] = bf16(A @ Wt^T) ------------------------------------------
// 128x128 tile, BK=64, 4 waves (2x2), 4x4 frags of 16x16x32.
// CVT=0: A bf16 via global_load_lds w16, double-buffered. CVT=1: A fp32 reg-staged+cvt.
// Block decode (1D grid 2048): n-tile pair of an m-panel on the same XCD (A L2 reuse).
#define GBK 64

template<bool CVT>
__global__ __launch_bounds__(256) void mgemm_kernel(
    const void* __restrict__ Ain,
    const unsigned short* __restrict__ Wt,
    unsigned short* __restrict__ C, int K)
{
    constexpr int NBUF = CVT ? 1 : 2;
    __shared__ unsigned short sA[NBUF][128 * GBK];
    __shared__ unsigned short sB[NBUF][128 * GBK];

    const int t = threadIdx.x;
    const int bid = blockIdx.x;
    const int xcd = bid & 7, kk_ = bid >> 3;
    const int m0 = ((kk_ >> 1) * 8 + xcd) * 128;
    const int n0 = (kk_ & 1) * 128;

    const int w = t >> 6, lane = t & 63;
    const int wr = w >> 1, wc = w & 1;
    const int lr = lane & 15, lk = lane >> 4;

    const int srow = lane >> 3;               // 0..7 within the 8-row group
    const int seg_src = (lane & 7) ^ srow;    // inverse-swizzled source segment

    f32x4 acc[4][4];
    #pragma unroll
    for (int i = 0; i < 4; ++i)
        #pragma unroll
        for (int j = 0; j < 4; ++j)
            acc[i][j] = (f32x4){0.f, 0.f, 0.f, 0.f};

    const int nsteps = K >> 6;

    auto stageB = [&](int buf, int k0) {
        #pragma unroll
        for (int i = 0; i < 4; ++i) {
            const int row = (w * 4 + i) * 8 + srow;
            const unsigned short* gb = Wt + (size_t)(n0 + row) * K + k0 + seg_src * 8;
            __builtin_amdgcn_global_load_lds(
                (const __attribute__((address_space(1))) unsigned int*)gb,
                (__attribute__((address_space(3))) unsigned int*)&sB[buf][(w * 4 + i) * 512],
                16, 0, 0);
        }
    };
    auto stageA_lds = [&](int buf, int k0) {
        #pragma unroll
        for (int i = 0; i < 4; ++i) {
            const int row = (w * 4 + i) * 8 + srow;
            const unsigned short* ga = (const unsigned short*)Ain + (size_t)(m0 + row) * K + k0 + seg_src * 8;
            __builtin_amdgcn_global_load_lds(
                (const __attribute__((address_space(1))) unsigned int*)ga,
                (__attribute__((address_space(3))) unsigned int*)&sA[buf][(w * 4 + i) * 512],
                16, 0, 0);
        }
    };

    auto compute = [&](int buf) {
        const char* pa = (const char*)sA[buf];
        const char* pb = (const char*)sB[buf];
        #pragma unroll
        for (int ks = 0; ks < 2; ++ks) {
            bf16x8 af[4], bfv[4];
            #pragma unroll
            for (int f = 0; f < 4; ++f) {
                const int ra = wr * 64 + f * 16 + lr;
                af[f] = *(const bf16x8*)(pa + ra * 128 + ((ks * 64 + lk * 16) ^ ((ra & 7) << 4)));
                const int rb = wc * 64 + f * 16 + lr;
                bfv[f] = *(const bf16x8*)(pb + rb * 128 + ((ks * 64 + lk * 16) ^ ((rb & 7) << 4)));
            }
            #pragma unroll
            for (int mf = 0; mf < 4; ++mf)
                #pragma unroll
                for (int nf = 0; nf < 4; ++nf)
                    acc[mf][nf] = __builtin_amdgcn_mfma_f32_16x16x32_bf16(
                        af[mf], bfv[nf], acc[mf][nf], 0, 0, 0);
        }
    };

    if constexpr (CVT) {
        const float* Af = (const float*)Ain;
        const int r = t >> 1, kh = (t & 1) * 32;   // this thread: row r, k-range [kh, kh+32)
        for (int s = 0; s < nsteps; ++s) {
            if (s > 0) __syncthreads();            // protect buffers from previous compute
            stageB(0, s * GBK);
            const float* ga = Af + (size_t)(m0 + r) * K + s * GBK + kh;
            #pragma unroll
            for (int j = 0; j < 4; ++j) {
                const float4 v0 = *(const float4*)(ga + j * 8);
                const float4 v1 = *(const float4*)(ga + j * 8 + 4);
                us8 o;
                o[0] = f2bf(v0.x); o[1] = f2bf(v0.y); o[2] = f2bf(v0.z); o[3] = f2bf(v0.w);
                o[4] = f2bf(v1.x); o[5] = f2bf(v1.y); o[6] = f2bf(v1.z); o[7] = f2bf(v1.w);
                const int slot = ((kh >> 3) + j) ^ (r & 7);
                *(us8*)&sA[0][r * 64 + slot * 8] = o;
            }
            __syncthreads();                       // drains B vmcnt + A lds writes
            compute(0);
        }
    } else {
        stageA_lds(0, 0);
        stageB(0, 0);
        __syncthreads();
        for (int s = 0; s < nsteps; ++s) {
            if (s + 1 < nsteps) { stageA_lds((s + 1) & 1, (s + 1) * GBK); stageB((s + 1) & 1, (s + 1) * GBK); }
            compute(s & 1);
            __syncthreads();
        }
    }

    // C/D layout: col = lane&15, row = (lane>>4)*4 + reg
    #pragma unroll
    for (int mf = 0; mf < 4; ++mf) {
        const int rbase = m0 + wr * 64 + mf * 16 + lk * 4;
        #pragma unroll
        for (int nf = 0; nf < 4; ++nf) {
            const int c = n0 + wc * 64 + nf * 16 + lr;
            #pragma unroll
            for (int r = 0; r < 4; ++r)
                C[(size_t)(rbase + r) * DHID + c] = f2bf(acc[mf][nf][r]);
        }
    }
}

// ---------------- SpMM: h = relu(Anorm @ hw + rowsum*c + b), vectorized 4-feat/lane --------------
// Lane l owns features 4l..4l+3 (8B uint2 loads); wave w owns 4 of the block's 16 nodes.
// Edge metadata packed (col,weight) in one uint2: single ds_read_b64 per edge.
// XCD-affine graph mapping keeps each graph's hw slab in one L2.
#define NB 16
#define ECAPB 512

template<bool STATS, bool OUTF32>
__global__ __launch_bounds__(256) void spmm_kernel(
    const unsigned short* __restrict__ hw, const float* __restrict__ bias,
    const float* __restrict__ rowsum, const float* __restrict__ cvec,
    void* __restrict__ hout, float* __restrict__ partials,
    const int* __restrict__ offs, const uint2* __restrict__ ecw)
{
    __shared__ uint2 sew[ECAPB];
    __shared__ int soff[NB + 1];
    __shared__ float spartS[4][256];
    __shared__ float spartQ[4][256];

    const int b = blockIdx.x;                 // 8192 blocks
    const int xcd = b & 7;
    const int idx = b >> 3;
    const int g  = (idx >> 6) * 8 + xcd;      // all 64 blocks of graph g on one XCD
    const int nb = (idx & 63) * NB;
    const int t = threadIdx.x;
    const int w = t >> 6, l = t & 63;
    const int f0 = l * 4;
    const unsigned short* __restrict__ hwg = hw + (size_t)g * NNODES * DHID;

    if (t <= NB) soff[t] = offs[nb + t];
    __syncthreads();
    const int base = soff[0];
    const int tot = soff[NB] - base;          // ~150, cap 512
    for (int e = t; e < tot; e += 256) sew[e] = ecw[base + e];
    __syncthreads();

    const float4 bv = *(const float4*)(bias + f0);
    const float4 cv = *(const float4*)(cvec + f0);
    float ps0=0, ps1=0, ps2=0, ps3=0, pq0=0, pq1=0, pq2=0, pq3=0;

    #pragma unroll 1
    for (int j = 0; j < 4; ++j) {
        const int i = w * 4 + j;
        const int s = soff[i] - base, e = soff[i + 1] - base;
        const float rs = rowsum[nb + i];
        float a0=0, a1=0, a2=0, a3=0;
        int k = s;
        #pragma unroll 1
        for (; k + 4 <= e; k += 4) {
            const uint2 p0 = sew[k+0], p1 = sew[k+1], p2 = sew[k+2], p3 = sew[k+3];
            const uint2 u0 = *(const uint2*)(hwg + (size_t)p0.x * DHID + f0);
            const uint2 u1 = *(const uint2*)(hwg + (size_t)p1.x * DHID + f0);
            const uint2 u2 = *(const uint2*)(hwg + (size_t)p2.x * DHID + f0);
            const uint2 u3 = *(const uint2*)(hwg + (size_t)p3.x * DHID + f0);
            const float w0 = __uint_as_float(p0.y), w1 = __uint_as_float(p1.y);
            const float w2 = __uint_as_float(p2.y), w3 = __uint_as_float(p3.y);
            a0 = fmaf(w0, blo(u0.x), a0); a1 = fmaf(w0, bhi(u0.x), a1);
            a2 = fmaf(w0, blo(u0.y), a2); a3 = fmaf(w0, bhi(u0.y), a3);
            a0 = fmaf(w1, blo(u1.x), a0); a1 = fmaf(w1, bhi(u1.x), a1);
            a2 = fmaf(w1, blo(u1.y), a2); a3 = fmaf(w1, bhi(u1.y), a3);
            a0 = fmaf(w2, blo(u2.x), a0); a1 = fmaf(w2, bhi(u2.x), a1);
            a2 = fmaf(w2, blo(u2.y), a2); a3 = fmaf(w2, bhi(u2.y), a3);
            a0 = fmaf(w3, blo(u3.x), a0); a1 = fmaf(w3, bhi(u3.x), a1);
            a2 = fmaf(w3, blo(u3.y), a2); a3 = fmaf(w3, bhi(u3.y), a3);
        }
        #pragma unroll 1
        for (; k < e; ++k) {
            const uint2 p = sew[k];
            const uint2 u = *(const uint2*)(hwg + (size_t)p.x * DHID + f0);
            const float wk = __uint_as_float(p.y);
            a0 = fmaf(wk, blo(u.x), a0); a1 = fmaf(wk, bhi(u.x), a1);
            a2 = fmaf(wk, blo(u.y), a2); a3 = fmaf(wk, bhi(u.y), a3);
        }

        const float v0 = fmaxf(fmaf(rs, cv.x, a0) + bv.x, 0.0f);
        const float v1 = fmaxf(fmaf(rs, cv.y, a1) + bv.y, 0.0f);
        const float v2 = fmaxf(fmaf(rs, cv.z, a2) + bv.z, 0.0f);
        const float v3 = fmaxf(fmaf(rs, cv.w, a3) + bv.w, 0.0f);
        const size_t orow = (size_t)g * NNODES + nb + i;
        if (OUTF32) {
            *(float4*)((float*)hout + orow * DHID + f0) = make_float4(v0, v1, v2, v3);
        } else {
            us4 o; o[0] = f2bf(v0); o[1] = f2bf(v1); o[2] = f2bf(v2); o[3] = f2bf(v3);
            *(us4*)((unsigned short*)hout + orow * DHID + f0) = o;
        }
        if (STATS) {
            ps0 += v0; ps1 += v1; ps2 += v2; ps3 += v3;
            pq0 += v0*v0; pq1 += v1*v1; pq2 += v2*v2; pq3 += v3*v3;
        }
    }

    if (STATS) {
        spartS[w][f0+0] = ps0; spartS[w][f0+1] = ps1; spartS[w][f0+2] = ps2; spartS[w][f0+3] = ps3;
        spartQ[w][f0+0] = pq0; spartQ[w][f0+1] = pq1; spartQ[w][f0+2] = pq2; spartQ[w][f0+3] = pq3;
        __syncthreads();
        const float ss = spartS[0][t] + spartS[1][t] + spartS[2][t] + spartS[3][t];
        const float sq = spartQ[0][t] + spartQ[1][t] + spartQ[2][t] + spartQ[3][t];
        partials[(size_t)b * 512 + t] = ss;
        partials[(size_t)b * 512 + 256 + t] = sq;
    }
}

// ---------------- stats reduce ------------------------------------------------------------------
__global__ __launch_bounds__(256) void reduce_kernel(
    const float* __restrict__ partials, float* __restrict__ stats, int P)
{
    const int t = threadIdx.x;
    const int per = P / gridDim.x;
    const int p0 = blockIdx.x * per;
    float s = 0.0f, q = 0.0f;
    for (int p = p0; p < p0 + per; ++p) {
        s += partials[(size_t)p * 512 + t];
        q += partials[(size_t)p * 512 + 256 + t];
    }
    atomicAdd(&stats[t], s);
    atomicAdd(&stats[256 + t], q);
}

// ---------------- launch -------------------------------------------------------------------------
extern "C" void kernel_launch(void* const* d_in, const int* in_sizes, int n_in,
                              void* d_out, int out_size, void* d_ws, size_t ws_size,
                              hipStream_t stream)
{
    const float* x      = (const float*)d_in[0];
    const int*   ei     = (const int*)d_in[1];
    const float* W1     = (const float*)d_in[3];
    const float* b1     = (const float*)d_in[4];
    const float* W2     = (const float*)d_in[5];
    const float* b2     = (const float*)d_in[6];
    const float* W3     = (const float*)d_in[7];
    const float* b3     = (const float*)d_in[8];
    const float* gamma1 = (const float*)d_in[9];
    const float* beta1  = (const float*)d_in[10];
    const float* gamma2 = (const float*)d_in[11];
    const float* beta2  = (const float*)d_in[12];
    float* out = (float*)d_out;

    const int E = in_sizes[1] / 2;   // 8192

    // workspace layout (total ~152 MB)
    char* w = (char*)d_ws;
    unsigned short* hA = (unsigned short*)w;                 // h bf16 (67 MB)
    unsigned short* hw = (unsigned short*)(w + 67108864);    // 67 MB
    float* partials    = (float*)(w + 134217728);            // 16.8 MB
    char* meta = w + 150994944;
    int*   offs   = (int*)meta;            meta += 4352;
    uint2* ecw    = (uint2*)meta;          meta += ECAP * 8;
    float* stats1 = (float*)meta;          meta += 512 * 4;   // stats1+stats2 contiguous (zeroed by build)
    float* stats2 = (float*)meta;          meta += 512 * 4;
    float* rowsum = (float*)meta;          meta += NNODES * 4;
    float* cvec1  = (float*)meta;          meta += 256 * 4;
    float* cvec2  = (float*)meta;          meta += 256 * 4;
    float* cvec3  = (float*)meta;          meta += 256 * 4;
    unsigned short* wt1 = (unsigned short*)meta;  meta += 256 * 128 * 2;
    unsigned short* wt2 = (unsigned short*)meta;  meta += 256 * 256 * 2;
    unsigned short* wt3 = (unsigned short*)meta;  meta += 256 * 256 * 2;

    const int GG = 2048;                 // 1D GEMM grid (pairing swizzle decoded in-kernel)
    const int P  = NTOTAL / NB;          // 8192

    build_kernel<<<1, 1024, 0, stream>>>(ei, E, offs, ecw, rowsum, stats1);
    wprep_kernel<<<DHID, 256, 0, stream>>>(W1, wt1, cvec1, FEAT_IN);

    // Layer 1 (x fp32 converted in-GEMM)
    mgemm_kernel<true><<<GG, 256, 0, stream>>>(x, wt1, hw, FEAT_IN);
    spmm_kernel<true, false><<<P, 256, 0, stream>>>(hw, b1, rowsum, cvec1, hA, partials, offs, ecw);
    reduce_kernel<<<64, 256, 0, stream>>>(partials, stats1, P);
    bnwprep_kernel<<<DHID, 256, 0, stream>>>(stats1, gamma1, beta1, W2, wt2, cvec2);

    // Layer 2
    mgemm_kernel<false><<<GG, 256, 0, stream>>>(hA, wt2, hw, DHID);
    spmm_kernel<true, false><<<P, 256, 0, stream>>>(hw, b2, rowsum, cvec2, hA, partials, offs, ecw);
    reduce_kernel<<<64, 256, 0, stream>>>(partials, stats2, P);
    bnwprep_kernel<<<DHID, 256, 0, stream>>>(stats2, gamma2, beta2, W3, wt3, cvec3);

    // Layer 3 (fp32 output, no stats)
    mgemm_kernel<false><<<GG, 256, 0, stream>>>(hA, wt3, hw, DHID);
    spmm_kernel<false, true><<<P, 256, 0, stream>>>(hw, b3, rowsum, cvec3, out, nullptr, offs, ecw);
}

// Round 11
// 347.786 us; speedup vs baseline: 1.0639x; 1.0038x over previous
//
#include <hip/hip_runtime.h>

// Problem constants (fixed instance):
//   B=128 graphs, N=1024 nodes/graph, F=128 in-feats, D=256 hidden, E=8192 edges/graph
#define NNODES   1024
#define NGRAPH   128
#define NTOTAL   (NNODES * NGRAPH)   // 131072
#define FEAT_IN  128
#define DHID     256
#define ECAP     (16384 + NNODES)    // CSR capacity
#define GBK      64

typedef __attribute__((ext_vector_type(8))) short bf16x8;
typedef __attribute__((ext_vector_type(4))) float f32x4;
typedef __attribute__((ext_vector_type(4))) unsigned short us4;
typedef __attribute__((ext_vector_type(8))) unsigned short us8;

__device__ __forceinline__ unsigned short f2bf(float f) {
    unsigned int u = __float_as_uint(f);
    u += 0x7fffu + ((u >> 16) & 1u);           // RNE
    return (unsigned short)(u >> 16);
}
__device__ __forceinline__ float blo(unsigned int u) { return __uint_as_float(u << 16); }
__device__ __forceinline__ float bhi(unsigned int u) { return __uint_as_float(u & 0xffff0000u); }

// Shared-memory union: GEMM staging vs builder scratch (block 0 only uses .b)
union SMU {
    struct { unsigned short sA[128 * GBK]; unsigned short sB[128 * GBK]; } g;   // 32 KB
    struct { int scnt[NNODES]; int psA[256]; int psB[256];
             float sdinv[NNODES]; float fb[NNODES]; } b;                        // 14 KB
};

// ---------------- W1 prep (no BN): Wt[n][k] = bf16(W[k][n]) ; cvec[n] = 0 ------------------------
__global__ __launch_bounds__(256) void wprep_kernel(
    const float* __restrict__ W, unsigned short* __restrict__ Wt,
    float* __restrict__ cvec, int K)
{
    const int n = blockIdx.x, k = threadIdx.x;
    if (k < K) Wt[(size_t)n * K + k] = f2bf(W[(size_t)k * DHID + n]);
    if (k == 0) cvec[n] = 0.0f;
}

// ---------------- fused BN-finalize + W prep -----------------------------------------------------
__global__ __launch_bounds__(256) void bnwprep_kernel(
    const float* __restrict__ stats, const float* __restrict__ gamma,
    const float* __restrict__ beta, const float* __restrict__ W,
    unsigned short* __restrict__ Wt, float* __restrict__ cvec)
{
    __shared__ float red[256];
    const int n = blockIdx.x, k = threadIdx.x;
    const float nn = (float)NTOTAL;
    const float mean = stats[k] / nn;
    const float var = stats[256 + k] / nn - mean * mean;
    const float sc = gamma[k] * rsqrtf(var + 1e-5f);
    const float sh = beta[k] - mean * sc;
    const float wv = W[(size_t)k * DHID + n];
    Wt[(size_t)n * DHID + k] = f2bf(sc * wv);
    red[k] = sh * wv;
    __syncthreads();
    for (int s = 128; s > 0; s >>= 1) {
        if (k < s) red[k] += red[k + s];
        __syncthreads();
    }
    if (k == 0) cvec[n] = red[0];
}

// ---------------- GEMM-1 (fp32 A, in-kernel cvt) + fused CSR builder (block 0) -------------------
// Blocks 1..2048: C[M][256] = bf16(x @ Wt^T), 128x128 tile, K=128, single-buffered,
//   B via global_load_lds w16, A reg-staged fp32->bf16 with XOR-swizzled LDS writes.
// Block 0: builds degree, dinv, CSR-by-dst (self-loops first), packed (col,weight),
//   rowsum, and zeroes stats — runs concurrently, hidden under the GEMM.
__global__ __launch_bounds__(256) void gemm1_kernel(
    const float* __restrict__ x, const unsigned short* __restrict__ Wt,
    unsigned short* __restrict__ C,
    const int* __restrict__ ei, int E,
    int* __restrict__ offs, uint2* __restrict__ ecw,
    float* __restrict__ rowsum, float* __restrict__ stats)
{
    __shared__ SMU sm;
    const int t = threadIdx.x;

    if (blockIdx.x == 0) {
        // ---------- builder (256 threads, 4 nodes/thread) ----------
        #pragma unroll
        for (int i = 0; i < 4; ++i) { sm.b.scnt[t * 4 + i] = 1; stats[t + 256 * i] = 0.0f; }
        __syncthreads();
        for (int e = t; e < E; e += 256) atomicAdd(&sm.b.scnt[ei[E + e]], 1);
        __syncthreads();
        int c[4]; int ssum = 0;
        #pragma unroll
        for (int i = 0; i < 4; ++i) { c[i] = sm.b.scnt[t * 4 + i]; ssum += c[i]; }
        sm.b.psA[t] = ssum;
        __syncthreads();
        int* src = sm.b.psA; int* dst = sm.b.psB;
        for (int d = 1; d < 256; d <<= 1) {          // 8 iters (even) -> result in psA
            dst[t] = src[t] + (t >= d ? src[t - d] : 0);
            __syncthreads();
            int* tmp = src; src = dst; dst = tmp;
        }
        int run = src[t] - ssum;                     // exclusive prefix of this 4-node group
        float di[4]; int pos[4];
        #pragma unroll
        for (int i = 0; i < 4; ++i) {
            offs[t * 4 + i] = run;
            di[i] = rsqrtf((float)c[i]);
            sm.b.sdinv[t * 4 + i] = di[i];
            pos[i] = run;
            run += c[i];
        }
        if (t == 255) offs[NNODES] = run;
        __syncthreads();
        #pragma unroll
        for (int i = 0; i < 4; ++i) {                // self loop first; cursor continues after it
            ecw[pos[i]] = make_uint2((unsigned)(t * 4 + i), __float_as_uint(di[i] * di[i]));
            sm.b.scnt[t * 4 + i] = pos[i] + 1;
            sm.b.fb[t * 4 + i] = di[i] * di[i];
        }
        __syncthreads();
        for (int e = t; e < E; e += 256) {
            const int sN = ei[e], dN = ei[E + e];
            const int p = atomicAdd(&sm.b.scnt[dN], 1);
            const float wv = sm.b.sdinv[sN] * sm.b.sdinv[dN];
            ecw[p] = make_uint2((unsigned)sN, __float_as_uint(wv));
            atomicAdd(&sm.b.fb[dN], wv);
        }
        __syncthreads();
        #pragma unroll
        for (int i = 0; i < 4; ++i) rowsum[t * 4 + i] = sm.b.fb[t * 4 + i];
        return;
    }

    // ---------- GEMM path ----------
    const int bid = blockIdx.x - 1;
    const int xcd = bid & 7, kk_ = bid >> 3;
    const int m0 = ((kk_ >> 1) * 8 + xcd) * 128;     // n-tile pair of an m-panel shares an XCD
    const int n0 = (kk_ & 1) * 128;
    const int K = FEAT_IN;

    const int w = t >> 6, lane = t & 63;
    const int wr = w >> 1, wc = w & 1;
    const int lr = lane & 15, lk = lane >> 4;
    const int srow = lane >> 3;
    const int seg_src = (lane & 7) ^ srow;           // inverse-swizzled source segment

    f32x4 acc[4][4];
    #pragma unroll
    for (int i = 0; i < 4; ++i)
        #pragma unroll
        for (int j = 0; j < 4; ++j)
            acc[i][j] = (f32x4){0.f, 0.f, 0.f, 0.f};

    const int r = t >> 1, kh = (t & 1) * 32;         // A-staging: row r, k-range [kh, kh+32)
    for (int s = 0; s < 2; ++s) {                    // K=128 -> 2 steps
        if (s > 0) __syncthreads();
        #pragma unroll
        for (int i = 0; i < 4; ++i) {
            const int row = (w * 4 + i) * 8 + srow;
            const unsigned short* gb = Wt + (size_t)(n0 + row) * K + s * GBK + seg_src * 8;
            __builtin_amdgcn_global_load_lds(
                (const __attribute__((address_space(1))) unsigned int*)gb,
                (__attribute__((address_space(3))) unsigned int*)&sm.g.sB[(w * 4 + i) * 512],
                16, 0, 0);
        }
        const float* ga = x + (size_t)(m0 + r) * K + s * GBK + kh;
        #pragma unroll
        for (int j = 0; j < 4; ++j) {
            const float4 v0 = *(const float4*)(ga + j * 8);
            const float4 v1 = *(const float4*)(ga + j * 8 + 4);
            us8 o;
            o[0] = f2bf(v0.x); o[1] = f2bf(v0.y); o[2] = f2bf(v0.z); o[3] = f2bf(v0.w);
            o[4] = f2bf(v1.x); o[5] = f2bf(v1.y); o[6] = f2bf(v1.z); o[7] = f2bf(v1.w);
            const int slot = ((kh >> 3) + j) ^ (r & 7);
            *(us8*)&sm.g.sA[r * 64 + slot * 8] = o;
        }
        __syncthreads();                             // drains B vmcnt + A lds writes
        const char* pa = (const char*)sm.g.sA;
        const char* pb = (const char*)sm.g.sB;
        #pragma unroll
        for (int ks = 0; ks < 2; ++ks) {
            bf16x8 af[4], bfv[4];
            #pragma unroll
            for (int f = 0; f < 4; ++f) {
                const int ra = wr * 64 + f * 16 + lr;
                af[f] = *(const bf16x8*)(pa + ra * 128 + ((ks * 64 + lk * 16) ^ ((ra & 7) << 4)));
                const int rb = wc * 64 + f * 16 + lr;
                bfv[f] = *(const bf16x8*)(pb + rb * 128 + ((ks * 64 + lk * 16) ^ ((rb & 7) << 4)));
            }
            #pragma unroll
            for (int mf = 0; mf < 4; ++mf)
                #pragma unroll
                for (int nf = 0; nf < 4; ++nf)
                    acc[mf][nf] = __builtin_amdgcn_mfma_f32_16x16x32_bf16(
                        af[mf], bfv[nf], acc[mf][nf], 0, 0, 0);
        }
    }

    // C/D layout: col = lane&15, row = (lane>>4)*4 + reg
    #pragma unroll
    for (int mf = 0; mf < 4; ++mf) {
        const int rbase = m0 + wr * 64 + mf * 16 + lk * 4;
        #pragma unroll
        for (int nf = 0; nf < 4; ++nf) {
            const int c = n0 + wc * 64 + nf * 16 + lr;
            #pragma unroll
            for (int rr = 0; rr < 4; ++rr)
                C[(size_t)(rbase + rr) * DHID + c] = f2bf(acc[mf][nf][rr]);
        }
    }
}

// ---------------- MFMA GEMM (layers 2/3): C[M][256] = bf16(A @ Wt^T), A bf16 ---------------------
// 128x128 tile, BK=64, double-buffered global_load_lds w16, XOR-swizzled reads.
__global__ __launch_bounds__(256) void mgemm_kernel(
    const unsigned short* __restrict__ Ain,
    const unsigned short* __restrict__ Wt,
    unsigned short* __restrict__ C, int K)
{
    __shared__ unsigned short sA[2][128 * GBK];
    __shared__ unsigned short sB[2][128 * GBK];

    const int t = threadIdx.x;
    const int bid = blockIdx.x;
    const int xcd = bid & 7, kk_ = bid >> 3;
    const int m0 = ((kk_ >> 1) * 8 + xcd) * 128;
    const int n0 = (kk_ & 1) * 128;

    const int w = t >> 6, lane = t & 63;
    const int wr = w >> 1, wc = w & 1;
    const int lr = lane & 15, lk = lane >> 4;
    const int srow = lane >> 3;
    const int seg_src = (lane & 7) ^ srow;

    f32x4 acc[4][4];
    #pragma unroll
    for (int i = 0; i < 4; ++i)
        #pragma unroll
        for (int j = 0; j < 4; ++j)
            acc[i][j] = (f32x4){0.f, 0.f, 0.f, 0.f};

    const int nsteps = K >> 6;

    auto stage = [&](int buf, int k0) {
        #pragma unroll
        for (int i = 0; i < 4; ++i) {
            const int row = (w * 4 + i) * 8 + srow;
            const unsigned short* ga = Ain + (size_t)(m0 + row) * K + k0 + seg_src * 8;
            __builtin_amdgcn_global_load_lds(
                (const __attribute__((address_space(1))) unsigned int*)ga,
                (__attribute__((address_space(3))) unsigned int*)&sA[buf][(w * 4 + i) * 512],
                16, 0, 0);
            const unsigned short* gb = Wt + (size_t)(n0 + row) * K + k0 + seg_src * 8;
            __builtin_amdgcn_global_load_lds(
                (const __attribute__((address_space(1))) unsigned int*)gb,
                (__attribute__((address_space(3))) unsigned int*)&sB[buf][(w * 4 + i) * 512],
                16, 0, 0);
        }
    };

    stage(0, 0);
    __syncthreads();
    for (int s = 0; s < nsteps; ++s) {
        if (s + 1 < nsteps) stage((s + 1) & 1, (s + 1) * GBK);
        const char* pa = (const char*)sA[s & 1];
        const char* pb = (const char*)sB[s & 1];
        #pragma unroll
        for (int ks = 0; ks < 2; ++ks) {
            bf16x8 af[4], bfv[4];
            #pragma unroll
            for (int f = 0; f < 4; ++f) {
                const int ra = wr * 64 + f * 16 + lr;
                af[f] = *(const bf16x8*)(pa + ra * 128 + ((ks * 64 + lk * 16) ^ ((ra & 7) << 4)));
                const int rb = wc * 64 + f * 16 + lr;
                bfv[f] = *(const bf16x8*)(pb + rb * 128 + ((ks * 64 + lk * 16) ^ ((rb & 7) << 4)));
            }
            #pragma unroll
            for (int mf = 0; mf < 4; ++mf)
                #pragma unroll
                for (int nf = 0; nf < 4; ++nf)
                    acc[mf][nf] = __builtin_amdgcn_mfma_f32_16x16x32_bf16(
                        af[mf], bfv[nf], acc[mf][nf], 0, 0, 0);
        }
        __syncthreads();
    }

    #pragma unroll
    for (int mf = 0; mf < 4; ++mf) {
        const int rbase = m0 + wr * 64 + mf * 16 + lk * 4;
        #pragma unroll
        for (int nf = 0; nf < 4; ++nf) {
            const int c = n0 + wc * 64 + nf * 16 + lr;
            #pragma unroll
            for (int rr = 0; rr < 4; ++rr)
                C[(size_t)(rbase + rr) * DHID + c] = f2bf(acc[mf][nf][rr]);
        }
    }
}

// ---------------- SpMM: h = relu(Anorm @ hw + rowsum*c + b), vectorized 4-feat/lane --------------
// Lane l owns features 4l..4l+3 (8B uint2 loads); wave w owns 4 of the block's 16 nodes.
// Edge metadata packed (col,weight) in one uint2: single ds_read_b64 per edge.
// XCD-affine graph mapping keeps each graph's hw slab in one L2.
#define NB 16
#define ECAPB 512

template<bool STATS, bool OUTF32>
__global__ __launch_bounds__(256) void spmm_kernel(
    const unsigned short* __restrict__ hw, const float* __restrict__ bias,
    const float* __restrict__ rowsum, const float* __restrict__ cvec,
    void* __restrict__ hout, float* __restrict__ partials,
    const int* __restrict__ offs, const uint2* __restrict__ ecw)
{
    __shared__ uint2 sew[ECAPB];
    __shared__ int soff[NB + 1];
    __shared__ float spartS[4][256];
    __shared__ float spartQ[4][256];

    const int b = blockIdx.x;                 // 8192 blocks
    const int xcd = b & 7;
    const int idx = b >> 3;
    const int g  = (idx >> 6) * 8 + xcd;      // all 64 blocks of graph g on one XCD
    const int nb = (idx & 63) * NB;
    const int t = threadIdx.x;
    const int w = t >> 6, l = t & 63;
    const int f0 = l * 4;
    const unsigned short* __restrict__ hwg = hw + (size_t)g * NNODES * DHID;

    if (t <= NB) soff[t] = offs[nb + t];
    __syncthreads();
    const int base = soff[0];
    const int tot = soff[NB] - base;          // ~150, cap 512
    for (int e = t; e < tot; e += 256) sew[e] = ecw[base + e];
    __syncthreads();

    const float4 bv = *(const float4*)(bias + f0);
    const float4 cv = *(const float4*)(cvec + f0);
    float ps0=0, ps1=0, ps2=0, ps3=0, pq0=0, pq1=0, pq2=0, pq3=0;

    #pragma unroll 1
    for (int j = 0; j < 4; ++j) {
        const int i = w * 4 + j;
        const int s = soff[i] - base, e = soff[i + 1] - base;
        const float rs = rowsum[nb + i];
        float a0=0, a1=0, a2=0, a3=0;
        int k = s;
        #pragma unroll 1
        for (; k + 4 <= e; k += 4) {
            const uint2 p0 = sew[k+0], p1 = sew[k+1], p2 = sew[k+2], p3 = sew[k+3];
            const uint2 u0 = *(const uint2*)(hwg + (size_t)p0.x * DHID + f0);
            const uint2 u1 = *(const uint2*)(hwg + (size_t)p1.x * DHID + f0);
            const uint2 u2 = *(const uint2*)(hwg + (size_t)p2.x * DHID + f0);
            const uint2 u3 = *(const uint2*)(hwg + (size_t)p3.x * DHID + f0);
            const float w0 = __uint_as_float(p0.y), w1 = __uint_as_float(p1.y);
            const float w2 = __uint_as_float(p2.y), w3 = __uint_as_float(p3.y);
            a0 = fmaf(w0, blo(u0.x), a0); a1 = fmaf(w0, bhi(u0.x), a1);
            a2 = fmaf(w0, blo(u0.y), a2); a3 = fmaf(w0, bhi(u0.y), a3);
            a0 = fmaf(w1, blo(u1.x), a0); a1 = fmaf(w1, bhi(u1.x), a1);
            a2 = fmaf(w1, blo(u1.y), a2); a3 = fmaf(w1, bhi(u1.y), a3);
            a0 = fmaf(w2, blo(u2.x), a0); a1 = fmaf(w2, bhi(u2.x), a1);
            a2 = fmaf(w2, blo(u2.y), a2); a3 = fmaf(w2, bhi(u2.y), a3);
            a0 = fmaf(w3, blo(u3.x), a0); a1 = fmaf(w3, bhi(u3.x), a1);
            a2 = fmaf(w3, blo(u3.y), a2); a3 = fmaf(w3, bhi(u3.y), a3);
        }
        #pragma unroll 1
        for (; k < e; ++k) {
            const uint2 p = sew[k];
            const uint2 u = *(const uint2*)(hwg + (size_t)p.x * DHID + f0);
            const float wk = __uint_as_float(p.y);
            a0 = fmaf(wk, blo(u.x), a0); a1 = fmaf(wk, bhi(u.x), a1);
            a2 = fmaf(wk, blo(u.y), a2); a3 = fmaf(wk, bhi(u.y), a3);
        }

        const float v0 = fmaxf(fmaf(rs, cv.x, a0) + bv.x, 0.0f);
        const float v1 = fmaxf(fmaf(rs, cv.y, a1) + bv.y, 0.0f);
        const float v2 = fmaxf(fmaf(rs, cv.z, a2) + bv.z, 0.0f);
        const float v3 = fmaxf(fmaf(rs, cv.w, a3) + bv.w, 0.0f);
        const size_t orow = (size_t)g * NNODES + nb + i;
        if (OUTF32) {
            *(float4*)((float*)hout + orow * DHID + f0) = make_float4(v0, v1, v2, v3);
        } else {
            us4 o; o[0] = f2bf(v0); o[1] = f2bf(v1); o[2] = f2bf(v2); o[3] = f2bf(v3);
            *(us4*)((unsigned short*)hout + orow * DHID + f0) = o;
        }
        if (STATS) {
            ps0 += v0; ps1 += v1; ps2 += v2; ps3 += v3;
            pq0 += v0*v0; pq1 += v1*v1; pq2 += v2*v2; pq3 += v3*v3;
        }
    }

    if (STATS) {
        spartS[w][f0+0] = ps0; spartS[w][f0+1] = ps1; spartS[w][f0+2] = ps2; spartS[w][f0+3] = ps3;
        spartQ[w][f0+0] = pq0; spartQ[w][f0+1] = pq1; spartQ[w][f0+2] = pq2; spartQ[w][f0+3] = pq3;
        __syncthreads();
        const float ss = spartS[0][t] + spartS[1][t] + spartS[2][t] + spartS[3][t];
        const float sq = spartQ[0][t] + spartQ[1][t] + spartQ[2][t] + spartQ[3][t];
        partials[(size_t)b * 512 + t] = ss;
        partials[(size_t)b * 512 + 256 + t] = sq;
    }
}

// ---------------- stats reduce ------------------------------------------------------------------
__global__ __launch_bounds__(256) void reduce_kernel(
    const float* __restrict__ partials, float* __restrict__ stats, int P)
{
    const int t = threadIdx.x;
    const int per = P / gridDim.x;
    const int p0 = blockIdx.x * per;
    float s = 0.0f, q = 0.0f;
    for (int p = p0; p < p0 + per; ++p) {
        s += partials[(size_t)p * 512 + t];
        q += partials[(size_t)p * 512 + 256 + t];
    }
    atomicAdd(&stats[t], s);
    atomicAdd(&stats[256 + t], q);
}

// ---------------- launch -------------------------------------------------------------------------
extern "C" void kernel_launch(void* const* d_in, const int* in_sizes, int n_in,
                              void* d_out, int out_size, void* d_ws, size_t ws_size,
                              hipStream_t stream)
{
    const float* x      = (const float*)d_in[0];
    const int*   ei     = (const int*)d_in[1];
    const float* W1     = (const float*)d_in[3];
    const float* b1     = (const float*)d_in[4];
    const float* W2     = (const float*)d_in[5];
    const float* b2     = (const float*)d_in[6];
    const float* W3     = (const float*)d_in[7];
    const float* b3     = (const float*)d_in[8];
    const float* gamma1 = (const float*)d_in[9];
    const float* beta1  = (const float*)d_in[10];
    const float* gamma2 = (const float*)d_in[11];
    const float* beta2  = (const float*)d_in[12];
    float* out = (float*)d_out;

    const int E = in_sizes[1] / 2;   // 8192

    // workspace layout (total ~152 MB)
    char* w = (char*)d_ws;
    unsigned short* hA = (unsigned short*)w;                 // h bf16 (67 MB)
    unsigned short* hw = (unsigned short*)(w + 67108864);    // 67 MB
    float* partials    = (float*)(w + 134217728);            // 16.8 MB
    char* meta = w + 150994944;
    int*   offs   = (int*)meta;            meta += 4352;
    uint2* ecw    = (uint2*)meta;          meta += ECAP * 8;
    float* stats1 = (float*)meta;          meta += 512 * 4;   // stats1+stats2 contiguous (zeroed by builder)
    float* stats2 = (float*)meta;          meta += 512 * 4;
    float* rowsum = (float*)meta;          meta += NNODES * 4;
    float* cvec1  = (float*)meta;          meta += 256 * 4;
    float* cvec2  = (float*)meta;          meta += 256 * 4;
    float* cvec3  = (float*)meta;          meta += 256 * 4;
    unsigned short* wt1 = (unsigned short*)meta;  meta += 256 * 128 * 2;
    unsigned short* wt2 = (unsigned short*)meta;  meta += 256 * 256 * 2;
    unsigned short* wt3 = (unsigned short*)meta;  meta += 256 * 256 * 2;

    const int GG = 2048;                 // GEMM blocks (pairing swizzle decoded in-kernel)
    const int P  = NTOTAL / NB;          // 8192

    wprep_kernel<<<DHID, 256, 0, stream>>>(W1, wt1, cvec1, FEAT_IN);

    // Layer 1: GEMM (x fp32 converted in-kernel) + CSR builder fused as block 0
    gemm1_kernel<<<GG + 1, 256, 0, stream>>>(x, wt1, hw, ei, E, offs, ecw, rowsum, stats1);
    spmm_kernel<true, false><<<P, 256, 0, stream>>>(hw, b1, rowsum, cvec1, hA, partials, offs, ecw);
    reduce_kernel<<<64, 256, 0, stream>>>(partials, stats1, P);
    bnwprep_kernel<<<DHID, 256, 0, stream>>>(stats1, gamma1, beta1, W2, wt2, cvec2);

    // Layer 2
    mgemm_kernel<<<GG, 256, 0, stream>>>(hA, wt2, hw, DHID);
    spmm_kernel<true, false><<<P, 256, 0, stream>>>(hw, b2, rowsum, cvec2, hA, partials, offs, ecw);
    reduce_kernel<<<64, 256, 0, stream>>>(partials, stats2, P);
    bnwprep_kernel<<<DHID, 256, 0, stream>>>(stats2, gamma2, beta2, W3, wt3, cvec3);

    // Layer 3 (fp32 output, no stats)
    mgemm_kernel<<<GG, 256, 0, stream>>>(hA, wt3, hw, DHID);
    spmm_kernel<false, true><<<P, 256, 0, stream>>>(hw, b3, rowsum, cvec3, out, nullptr, offs, ecw);
}